// Round 1
// baseline (21356.172 us; speedup 1.0000x reference)
//
#include <hip/hip_runtime.h>
#include <cstddef>
#include <cstdint>
#include <cmath>

// Problem constants (from reference)
#define BDIM  64
#define SDIM  1024
#define DDIM  200
#define CDIM  31
#define NSTACK 2
#define EPS   1e-5f
#define LN_CHUNKS 32

// ---------------- Wm_eff = sum of 8 [200,200] row-blocks of Wm [1600,200] --------
// tile(c,(1,1,8)) @ Wm == c @ Wm_eff with Wm_eff[i,j] = sum_k Wm[k*200+i, j]
__global__ void wmeff_kernel(const float* __restrict__ Wm, float* __restrict__ wmeff)
{
    int idx = blockIdx.x * blockDim.x + threadIdx.x;
    if (idx < DDIM * DDIM) {
        int i = idx / DDIM, j = idx - i * DDIM;
        float s = 0.f;
        #pragma unroll
        for (int k = 0; k < 8; ++k)
            s += Wm[(size_t)(k * DDIM + i) * DDIM + j];
        wmeff[idx] = s;
    }
}

// ---------------- h = embed[x] + pos ----------------
__global__ void embed_kernel(const int* __restrict__ x, const float* __restrict__ embed,
                             const float* __restrict__ pos, float* __restrict__ h, int total)
{
    for (int idx = blockIdx.x * blockDim.x + threadIdx.x; idx < total;
         idx += gridDim.x * blockDim.x) {
        int row = idx / DDIM;          // b*S + s
        int e   = idx - row * DDIM;
        int s   = row & (SDIM - 1);
        int tok = x[row];
        h[idx] = embed[(size_t)tok * DDIM + e] + pos[(size_t)s * DDIM + e];
    }
}

// ---------------- fp32 tiled GEMM: C = A[M,K] @ B[K,N] + bias (+relu) (+res) ----
// BM=BN=64, BK=8, 256 threads, 4x4 per thread. M%64==0, K%8==0 assumed; N masked.
__global__ void gemm_kernel(const float* __restrict__ A, const float* __restrict__ B,
                            const float* __restrict__ bias, const float* __restrict__ res,
                            float* __restrict__ C, int M, int N, int K, int doRelu)
{
    __shared__ float As[8][64];
    __shared__ float Bs[8][65];
    const int bm = blockIdx.y * 64;
    const int bn = blockIdx.x * 64;
    const int tid = threadIdx.x;
    const int tr = tid >> 4, tc = tid & 15;
    float acc[4][4] = {{0.f}};
    for (int k0 = 0; k0 < K; k0 += 8) {
        for (int i = tid; i < 512; i += 256) {
            int r = i >> 3, kk = i & 7;
            As[kk][r] = A[(size_t)(bm + r) * K + (k0 + kk)];
        }
        for (int i = tid; i < 512; i += 256) {
            int kk = i >> 6, cc = i & 63;
            int col = bn + cc;
            Bs[kk][cc] = (col < N) ? B[(size_t)(k0 + kk) * N + col] : 0.f;
        }
        __syncthreads();
        #pragma unroll
        for (int kk = 0; kk < 8; ++kk) {
            float a[4], b[4];
            #pragma unroll
            for (int i = 0; i < 4; ++i) a[i] = As[kk][tr * 4 + i];
            #pragma unroll
            for (int j = 0; j < 4; ++j) b[j] = Bs[kk][tc * 4 + j];
            #pragma unroll
            for (int i = 0; i < 4; ++i)
                #pragma unroll
                for (int j = 0; j < 4; ++j)
                    acc[i][j] = fmaf(a[i], b[j], acc[i][j]);
        }
        __syncthreads();
    }
    for (int i = 0; i < 4; ++i) {
        size_t row = (size_t)bm + tr * 4 + i;
        for (int j = 0; j < 4; ++j) {
            int col = bn + tc * 4 + j;
            if (col < N) {
                float v = acc[i][j] + bias[col];
                if (doRelu) v = fmaxf(v, 0.f);
                if (res) v += res[row * N + col];
                C[row * N + col] = v;
            }
        }
    }
}

// ---------------- attention: c[b,s,:] = softmax(p_b p_b^T / scale)[s,:] @ p_b ----
// one block per (s, b); q=k=v=p
__global__ void attn_kernel(const float* __restrict__ p, float* __restrict__ c, float inv_scale)
{
    const int b = blockIdx.y, s = blockIdx.x;
    const float* pb = p + (size_t)b * SDIM * DDIM;
    __shared__ float q[DDIM];
    __shared__ float sc[SDIM];
    __shared__ float red[256];
    const int tid = threadIdx.x;
    for (int d = tid; d < DDIM; d += 256) q[d] = pb[(size_t)s * DDIM + d];
    __syncthreads();

    // scores: each wave handles a contiguous 256-key range, 64 lanes per dot
    const int wave = tid >> 6, lane = tid & 63;
    for (int t0 = wave * (SDIM / 4); t0 < (wave + 1) * (SDIM / 4); ++t0) {
        const float* row = pb + (size_t)t0 * DDIM;
        float partial = 0.f;
        for (int d = lane; d < DDIM; d += 64) partial = fmaf(q[d], row[d], partial);
        #pragma unroll
        for (int off = 32; off; off >>= 1) partial += __shfl_down(partial, off);
        if (lane == 0) sc[t0] = partial * inv_scale;
    }
    __syncthreads();

    // softmax over sc[0..S)
    float m = -1e30f;
    for (int t = tid; t < SDIM; t += 256) m = fmaxf(m, sc[t]);
    red[tid] = m; __syncthreads();
    for (int w = 128; w; w >>= 1) { if (tid < w) red[tid] = fmaxf(red[tid], red[tid + w]); __syncthreads(); }
    m = red[0]; __syncthreads();
    float sum = 0.f;
    for (int t = tid; t < SDIM; t += 256) { float e = __expf(sc[t] - m); sc[t] = e; sum += e; }
    red[tid] = sum; __syncthreads();
    for (int w = 128; w; w >>= 1) { if (tid < w) red[tid] += red[tid + w]; __syncthreads(); }
    const float inv_sum = 1.f / red[0];
    __syncthreads();

    // c[d] = (1/sum) * sum_t sc[t] * p[t,d]  -- coalesced row reads across d
    if (tid < DDIM) {
        float acc = 0.f;
        for (int t = 0; t < SDIM; ++t) acc = fmaf(sc[t], pb[(size_t)t * DDIM + tid], acc);
        c[((size_t)b * SDIM + s) * DDIM + tid] = acc * inv_sum;
    }
}

// ---------------- LN over (S,D) jointly per batch: partial sums ----------------
__global__ void ln_partial(const float* __restrict__ t, float2* __restrict__ partials)
{
    const int b = blockIdx.y, ch = blockIdx.x;
    const int per = SDIM * DDIM / LN_CHUNKS;   // 6400
    const float* base = t + (size_t)b * SDIM * DDIM + (size_t)ch * per;
    float s = 0.f, s2 = 0.f;
    for (int i = threadIdx.x; i < per; i += 256) {
        float v = base[i]; s += v; s2 = fmaf(v, v, s2);
    }
    __shared__ float rs[256], rq[256];
    rs[threadIdx.x] = s; rq[threadIdx.x] = s2; __syncthreads();
    for (int w = 128; w; w >>= 1) {
        if (threadIdx.x < w) { rs[threadIdx.x] += rs[threadIdx.x + w]; rq[threadIdx.x] += rq[threadIdx.x + w]; }
        __syncthreads();
    }
    if (threadIdx.x == 0) partials[b * LN_CHUNKS + ch] = make_float2(rs[0], rq[0]);
}

__global__ void ln_norm(const float* __restrict__ t, const float2* __restrict__ partials,
                        float* __restrict__ o)
{
    const int b = blockIdx.y;
    float s = 0.f, s2 = 0.f;
    for (int i = 0; i < LN_CHUNKS; ++i) { float2 v = partials[b * LN_CHUNKS + i]; s += v.x; s2 += v.y; }
    const float n = (float)(SDIM * DDIM);
    const float mean = s / n;
    const float inv = rsqrtf(s2 / n - mean * mean + EPS);
    const size_t base = (size_t)b * SDIM * DDIM;
    for (int i = blockIdx.x * blockDim.x + threadIdx.x; i < SDIM * DDIM;
         i += gridDim.x * blockDim.x)
        o[base + i] = (t[base + i] - mean) * inv;
}

// ---------------- final: normalize row S-1 only, then @ Wd + bd ----------------
__global__ void final_kernel(const float* __restrict__ t, const float2* __restrict__ partials,
                             const float* __restrict__ Wd, const float* __restrict__ bd,
                             float* __restrict__ out)
{
    const int b = blockIdx.x;
    float s = 0.f, s2 = 0.f;
    for (int i = 0; i < LN_CHUNKS; ++i) { float2 v = partials[b * LN_CHUNKS + i]; s += v.x; s2 += v.y; }
    const float n = (float)(SDIM * DDIM);
    const float mean = s / n;
    const float inv = rsqrtf(s2 / n - mean * mean + EPS);
    __shared__ float hrow[DDIM];
    const float* row = t + (size_t)b * SDIM * DDIM + (size_t)(SDIM - 1) * DDIM;
    for (int d = threadIdx.x; d < DDIM; d += blockDim.x) hrow[d] = (row[d] - mean) * inv;
    __syncthreads();
    if (threadIdx.x < CDIM) {
        float acc = bd[threadIdx.x];
        for (int d = 0; d < DDIM; ++d)
            acc = fmaf(hrow[d], Wd[(size_t)d * CDIM + threadIdx.x], acc);
        out[(size_t)b * CDIM + threadIdx.x] = acc;
    }
}

extern "C" void kernel_launch(void* const* d_in, const int* in_sizes, int n_in,
                              void* d_out, int out_size, void* d_ws, size_t ws_size,
                              hipStream_t stream)
{
    const int*   x     = (const int*)  d_in[0];
    const float* embed = (const float*)d_in[1];
    const float* pos   = (const float*)d_in[2];
    const float* Wp    = (const float*)d_in[3];
    const float* bp    = (const float*)d_in[4];
    const float* Wm    = (const float*)d_in[5];
    const float* bm    = (const float*)d_in[6];
    const float* W1    = (const float*)d_in[7];
    const float* b1    = (const float*)d_in[8];
    const float* W2    = (const float*)d_in[9];
    const float* b2    = (const float*)d_in[10];
    const float* Wd    = (const float*)d_in[11];
    const float* bd    = (const float*)d_in[12];
    float* out = (float*)d_out;

    const size_t TOK = (size_t)BDIM * SDIM;   // 65536
    const size_t HSZ = TOK * DDIM;            // 13,107,200 floats
    float*  h     = (float*)d_ws;
    float*  p     = h + HSZ;
    float*  cb    = p + HSZ;
    float*  wmeff = cb + HSZ;
    float2* parts = (float2*)(wmeff + DDIM * DDIM);
    const size_t need = (3 * HSZ + (size_t)DDIM * DDIM) * sizeof(float)
                      + (size_t)BDIM * LN_CHUNKS * sizeof(float2);
    if (ws_size < need) return;  // scratch too small -> bench will flag failure

    wmeff_kernel<<<dim3((DDIM * DDIM + 255) / 256), dim3(256), 0, stream>>>(Wm, wmeff);
    embed_kernel<<<dim3(8192), dim3(256), 0, stream>>>(x, embed, pos, h, (int)HSZ);

    const float inv_scale = 1.0f / sqrtf((float)DDIM);
    const dim3 ggrid(4, 1024);   // N-tiles x M-tiles for M=65536, N=200

    for (int st = 0; st < NSTACK; ++st) {
        // p = h @ Wp + bp
        gemm_kernel<<<ggrid, 256, 0, stream>>>(h, Wp, bp, nullptr, p, (int)TOK, DDIM, DDIM, 0);
        // cb = softmax(p p^T / scale) @ p
        attn_kernel<<<dim3(SDIM, BDIM), 256, 0, stream>>>(p, cb, inv_scale);
        // p(reuse) = cb @ Wm_eff + bm + h     (residual)
        gemm_kernel<<<ggrid, 256, 0, stream>>>(cb, wmeff, bm, h, p, (int)TOK, DDIM, DDIM, 0);
        // h = LN2d(p)
        ln_partial<<<dim3(LN_CHUNKS, BDIM), 256, 0, stream>>>(p, parts);
        ln_norm<<<dim3(32, BDIM), 256, 0, stream>>>(p, parts, h);
        // cb = relu(h @ W1 + b1)
        gemm_kernel<<<ggrid, 256, 0, stream>>>(h, W1, b1, nullptr, cb, (int)TOK, DDIM, DDIM, 1);
        // p = cb @ W2 + b2 + h
        gemm_kernel<<<ggrid, 256, 0, stream>>>(cb, W2, b2, h, p, (int)TOK, DDIM, DDIM, 0);
        ln_partial<<<dim3(LN_CHUNKS, BDIM), 256, 0, stream>>>(p, parts);
        if (st < NSTACK - 1) {
            // h = LN2d(p)
            ln_norm<<<dim3(32, BDIM), 256, 0, stream>>>(p, parts, h);
        } else {
            // only row S-1 of the final LN is consumed -> fuse with head projection
            final_kernel<<<dim3(BDIM), 64, 0, stream>>>(p, parts, Wd, bd, out);
        }
    }
}

// Round 2
// 1889.938 us; speedup vs baseline: 11.2999x; 11.2999x over previous
//
#include <hip/hip_runtime.h>
#include <cstddef>
#include <cstdint>
#include <cmath>

// Problem constants (from reference)
#define BDIM  64
#define SDIM  1024
#define DDIM  200
#define DPAD  224            // padded feature dim: 7 x 32 (QK k-steps), 13+ x 16 n-tiles
#define CDIM  31
#define NSTACK 2
#define EPS   1e-5f
#define LN_CHUNKS 32

typedef __attribute__((ext_vector_type(8))) short short8;
typedef __attribute__((ext_vector_type(4))) float f32x4;

__device__ __forceinline__ short f2bf(float f) {
    union { float f; unsigned u; } v; v.f = f;
    unsigned r = v.u + 0x7FFFu + ((v.u >> 16) & 1u);   // RNE
    return (short)(r >> 16);
}

// ---------------- Wm_eff: tile(c,8) @ Wm == c @ Wm_eff ----------------
__global__ void wmeff_kernel(const float* __restrict__ Wm, float* __restrict__ wmeff)
{
    int idx = blockIdx.x * blockDim.x + threadIdx.x;
    if (idx < DDIM * DDIM) {
        int i = idx / DDIM, j = idx - i * DDIM;
        float s = 0.f;
        #pragma unroll
        for (int k = 0; k < 8; ++k)
            s += Wm[(size_t)(k * DDIM + i) * DDIM + j];
        wmeff[idx] = s;
    }
}

// ---------------- h = embed[x] + pos ----------------
__global__ void embed_kernel(const int* __restrict__ x, const float* __restrict__ embed,
                             const float* __restrict__ pos, float* __restrict__ h, int total)
{
    for (int idx = blockIdx.x * blockDim.x + threadIdx.x; idx < total;
         idx += gridDim.x * blockDim.x) {
        int row = idx / DDIM;
        int e   = idx - row * DDIM;
        int s   = row & (SDIM - 1);
        int tok = x[row];
        h[idx] = embed[(size_t)tok * DDIM + e] + pos[(size_t)s * DDIM + e];
    }
}

// ---------------- fp32 tiled GEMM (unchanged this round) ----------------
__global__ void gemm_kernel(const float* __restrict__ A, const float* __restrict__ B,
                            const float* __restrict__ bias, const float* __restrict__ res,
                            float* __restrict__ C, int M, int N, int K, int doRelu)
{
    __shared__ float As[8][64];
    __shared__ float Bs[8][65];
    const int bm = blockIdx.y * 64;
    const int bn = blockIdx.x * 64;
    const int tid = threadIdx.x;
    const int tr = tid >> 4, tc = tid & 15;
    float acc[4][4] = {{0.f}};
    for (int k0 = 0; k0 < K; k0 += 8) {
        for (int i = tid; i < 512; i += 256) {
            int r = i >> 3, kk = i & 7;
            As[kk][r] = A[(size_t)(bm + r) * K + (k0 + kk)];
        }
        for (int i = tid; i < 512; i += 256) {
            int kk = i >> 6, cc = i & 63;
            int col = bn + cc;
            Bs[kk][cc] = (col < N) ? B[(size_t)(k0 + kk) * N + col] : 0.f;
        }
        __syncthreads();
        #pragma unroll
        for (int kk = 0; kk < 8; ++kk) {
            float a[4], b[4];
            #pragma unroll
            for (int i = 0; i < 4; ++i) a[i] = As[kk][tr * 4 + i];
            #pragma unroll
            for (int j = 0; j < 4; ++j) b[j] = Bs[kk][tc * 4 + j];
            #pragma unroll
            for (int i = 0; i < 4; ++i)
                #pragma unroll
                for (int j = 0; j < 4; ++j)
                    acc[i][j] = fmaf(a[i], b[j], acc[i][j]);
        }
        __syncthreads();
    }
    for (int i = 0; i < 4; ++i) {
        size_t row = (size_t)bm + tr * 4 + i;
        for (int j = 0; j < 4; ++j) {
            int col = bn + tc * 4 + j;
            if (col < N) {
                float v = acc[i][j] + bias[col];
                if (doRelu) v = fmaxf(v, 0.f);
                if (res) v += res[row * N + col];
                C[row * N + col] = v;
            }
        }
    }
}

// ---------------- pack p -> bf16 [B,S,224] (zero-pad) and p_t [B,224,S] ----------
__global__ void pack_transpose_kernel(const float* __restrict__ p,
                                      short* __restrict__ pbf, short* __restrict__ pt)
{
    __shared__ short T[32][33];
    const int b  = blockIdx.z;
    const int s0 = blockIdx.x * 32;
    const int d0 = blockIdx.y * 32;
    const int tid = threadIdx.x;
    for (int i = tid; i < 1024; i += 256) {
        int r = i >> 5, cth = i & 31;
        int d = d0 + cth;
        float v = (d < DDIM) ? p[((size_t)b * SDIM + s0 + r) * DDIM + d] : 0.f;
        T[r][cth] = f2bf(v);
    }
    __syncthreads();
    for (int i = tid; i < 1024; i += 256) {
        int r = i >> 5, cth = i & 31;
        pbf[((size_t)b * SDIM + s0 + r) * DPAD + d0 + cth] = T[r][cth];
    }
    for (int i = tid; i < 1024; i += 256) {
        int dd = i >> 5, ss = i & 31;
        pt[((size_t)b * DPAD + d0 + dd) * SDIM + s0 + ss] = T[ss][dd];
    }
}

// ---------------- fused MFMA flash attention ----------------
// grid: 512 blocks x 256 threads (4 waves). Each block: 128 q-rows of one batch.
// Each wave: 32 q-rows as 2 row-tiles (rt) of 16. K-tiles of 64 keys, 16 tiles.
// K staged row-major [64][232] (pad->bank-free); V^T staged [208][64] XOR-swizzled.
// P (softmaxed probs, bf16) aliases the K region after the QK barrier.
#define KSTRIDE 232
__global__ __launch_bounds__(256, 2)
void attn_kernel(const short* __restrict__ pbf, const short* __restrict__ pt,
                 float* __restrict__ c, float inv_scale)
{
    __shared__ short K_lds[64 * KSTRIDE];   // 29696 B ; first 8192 elems alias P
    __shared__ short Vt_lds[208 * 64];      // 26624 B

    // XCD chunk swizzle: batch b's 8 q-blocks land on one XCD
    const int bid = blockIdx.x;
    const int wg  = (bid & 7) * 64 + (bid >> 3);
    const int b   = wg >> 3;
    const int q0  = (wg & 7) * 128;

    const int tid  = threadIdx.x;
    const int wave = tid >> 6;
    const int lane = tid & 63;
    const int lo   = lane & 15;
    const int hi   = lane >> 4;

    const short* pb  = pbf + (size_t)b * SDIM * DPAD;
    const short* ptb = pt  + (size_t)b * DPAD * SDIM;

    // Q fragments in registers: qf[rt][ks], row = q0 + wave*32 + rt*16 + lo
    short8 qf[2][7];
    #pragma unroll
    for (int rt = 0; rt < 2; ++rt)
        #pragma unroll
        for (int ks = 0; ks < 7; ++ks)
            qf[rt][ks] = *(const short8*)(pb + (size_t)(q0 + wave * 32 + rt * 16 + lo) * DPAD
                                          + ks * 32 + hi * 8);

    f32x4 o[2][13];
    float m[2][4], ell[2][4];
    #pragma unroll
    for (int rt = 0; rt < 2; ++rt) {
        #pragma unroll
        for (int n = 0; n < 13; ++n) o[rt][n] = (f32x4){0.f, 0.f, 0.f, 0.f};
        #pragma unroll
        for (int r = 0; r < 4; ++r) { m[rt][r] = -1e30f; ell[rt][r] = 0.f; }
    }

    for (int kt = 0; kt < 16; ++kt) {
        const int k0 = kt * 64;
        __syncthreads();   // previous PV reads (K-alias P + Vt) complete

        // stage K tile [64][224] -> K_lds stride 232
        for (int i = tid; i < 1792; i += 256) {
            int r  = i / 28;
            int c8 = i - r * 28;
            short8 v = *(const short8*)(pb + (size_t)(k0 + r) * DPAD + c8 * 8);
            *(short8*)(&K_lds[r * KSTRIDE + c8 * 8]) = v;
        }
        // stage V^T tile [208][64] swizzled
        for (int i = tid; i < 1664; i += 256) {
            int d  = i >> 3;
            int c8 = i & 7;
            short8 v = *(const short8*)(ptb + (size_t)d * SDIM + k0 + c8 * 8);
            int e = (d * 64 + c8 * 8) ^ ((d & 7) << 3);
            *(short8*)(&Vt_lds[e]) = v;
        }
        __syncthreads();

        // QK^T: sacc[rt][t] = Q[rt] . K[t]^T, k-frag reused across both rt
        f32x4 sacc[2][4];
        #pragma unroll
        for (int rt = 0; rt < 2; ++rt)
            #pragma unroll
            for (int t = 0; t < 4; ++t) sacc[rt][t] = (f32x4){0.f, 0.f, 0.f, 0.f};
        #pragma unroll
        for (int t = 0; t < 4; ++t)
            #pragma unroll
            for (int ks = 0; ks < 7; ++ks) {
                short8 kf = *(const short8*)(&K_lds[(t * 16 + lo) * KSTRIDE + ks * 32 + hi * 8]);
                sacc[0][t] = __builtin_amdgcn_mfma_f32_16x16x32_bf16(qf[0][ks], kf, sacc[0][t], 0, 0, 0);
                sacc[1][t] = __builtin_amdgcn_mfma_f32_16x16x32_bf16(qf[1][ks], kf, sacc[1][t], 0, 0, 0);
            }
        __syncthreads();   // all waves done reading K; P may now overwrite K region

        // online softmax per row-tile; write P (bf16) into K-alias region
        #pragma unroll
        for (int rt = 0; rt < 2; ++rt) {
            float mx[4], al[4], rs[4];
            #pragma unroll
            for (int t = 0; t < 4; ++t)
                #pragma unroll
                for (int r = 0; r < 4; ++r) sacc[rt][t][r] *= inv_scale;
            #pragma unroll
            for (int r = 0; r < 4; ++r)
                mx[r] = fmaxf(fmaxf(sacc[rt][0][r], sacc[rt][1][r]),
                              fmaxf(sacc[rt][2][r], sacc[rt][3][r]));
            #pragma unroll
            for (int off = 1; off <= 8; off <<= 1)
                #pragma unroll
                for (int r = 0; r < 4; ++r)
                    mx[r] = fmaxf(mx[r], __shfl_xor(mx[r], off));
            #pragma unroll
            for (int r = 0; r < 4; ++r) {
                float mn = fmaxf(m[rt][r], mx[r]);
                al[r] = __expf(m[rt][r] - mn);
                m[rt][r] = mn;
                ell[rt][r] *= al[r];
            }
            #pragma unroll
            for (int t = 0; t < 4; ++t)
                #pragma unroll
                for (int r = 0; r < 4; ++r)
                    sacc[rt][t][r] = __expf(sacc[rt][t][r] - m[rt][r]);
            #pragma unroll
            for (int r = 0; r < 4; ++r) {
                rs[r] = sacc[rt][0][r] + sacc[rt][1][r] + sacc[rt][2][r] + sacc[rt][3][r];
            }
            #pragma unroll
            for (int off = 1; off <= 8; off <<= 1)
                #pragma unroll
                for (int r = 0; r < 4; ++r)
                    rs[r] += __shfl_xor(rs[r], off);
            #pragma unroll
            for (int r = 0; r < 4; ++r) ell[rt][r] += rs[r];
            // rescale O
            #pragma unroll
            for (int n = 0; n < 13; ++n)
                #pragma unroll
                for (int r = 0; r < 4; ++r) o[rt][n][r] *= al[r];
            // write P
            const int pbase = wave * 2048 + rt * 1024;
            #pragma unroll
            for (int t = 0; t < 4; ++t)
                #pragma unroll
                for (int r = 0; r < 4; ++r) {
                    int qrow = hi * 4 + r;
                    int e = pbase + ((qrow * 64 + t * 16 + lo) ^ ((qrow & 7) << 3));
                    K_lds[e] = f2bf(sacc[rt][t][r]);
                }
        }

        // PV: O += P . V  (V^T fragments reused across both rt)
        #pragma unroll
        for (int ks2 = 0; ks2 < 2; ++ks2) {
            const int poff = (lo * 64 + ks2 * 32 + hi * 8) ^ ((lo & 7) << 3);
            short8 pa0 = *(const short8*)(&K_lds[wave * 2048 + poff]);
            short8 pa1 = *(const short8*)(&K_lds[wave * 2048 + 1024 + poff]);
            #pragma unroll
            for (int n = 0; n < 13; ++n) {
                short8 vf = *(const short8*)(&Vt_lds[((n * 16 + lo) * 64 + ks2 * 32 + hi * 8)
                                                     ^ ((lo & 7) << 3)]);
                o[0][n] = __builtin_amdgcn_mfma_f32_16x16x32_bf16(pa0, vf, o[0][n], 0, 0, 0);
                o[1][n] = __builtin_amdgcn_mfma_f32_16x16x32_bf16(pa1, vf, o[1][n], 0, 0, 0);
            }
        }
    }

    // epilogue: O /= ell, store fp32
    #pragma unroll
    for (int rt = 0; rt < 2; ++rt) {
        float inv_l[4];
        #pragma unroll
        for (int r = 0; r < 4; ++r) inv_l[r] = 1.f / ell[rt][r];
        #pragma unroll
        for (int n = 0; n < 13; ++n) {
            int dcol = n * 16 + lo;
            if (dcol < DDIM) {
                #pragma unroll
                for (int r = 0; r < 4; ++r) {
                    size_t row = (size_t)b * SDIM + q0 + wave * 32 + rt * 16 + hi * 4 + r;
                    c[row * DDIM + dcol] = o[rt][n][r] * inv_l[r];
                }
            }
        }
    }
}

// ---------------- LN over (S,D) jointly per batch ----------------
__global__ void ln_partial(const float* __restrict__ t, float2* __restrict__ partials)
{
    const int b = blockIdx.y, ch = blockIdx.x;
    const int per = SDIM * DDIM / LN_CHUNKS;
    const float* base = t + (size_t)b * SDIM * DDIM + (size_t)ch * per;
    float s = 0.f, s2 = 0.f;
    for (int i = threadIdx.x; i < per; i += 256) {
        float v = base[i]; s += v; s2 = fmaf(v, v, s2);
    }
    __shared__ float rs[256], rq[256];
    rs[threadIdx.x] = s; rq[threadIdx.x] = s2; __syncthreads();
    for (int w = 128; w; w >>= 1) {
        if (threadIdx.x < w) { rs[threadIdx.x] += rs[threadIdx.x + w]; rq[threadIdx.x] += rq[threadIdx.x + w]; }
        __syncthreads();
    }
    if (threadIdx.x == 0) partials[b * LN_CHUNKS + ch] = make_float2(rs[0], rq[0]);
}

__global__ void ln_norm(const float* __restrict__ t, const float2* __restrict__ partials,
                        float* __restrict__ o)
{
    const int b = blockIdx.y;
    float s = 0.f, s2 = 0.f;
    for (int i = 0; i < LN_CHUNKS; ++i) { float2 v = partials[b * LN_CHUNKS + i]; s += v.x; s2 += v.y; }
    const float n = (float)(SDIM * DDIM);
    const float mean = s / n;
    const float inv = rsqrtf(s2 / n - mean * mean + EPS);
    const size_t base = (size_t)b * SDIM * DDIM;
    for (int i = blockIdx.x * blockDim.x + threadIdx.x; i < SDIM * DDIM;
         i += gridDim.x * blockDim.x)
        o[base + i] = (t[base + i] - mean) * inv;
}

// ---------------- final: normalize row S-1 only + head ----------------
__global__ void final_kernel(const float* __restrict__ t, const float2* __restrict__ partials,
                             const float* __restrict__ Wd, const float* __restrict__ bd,
                             float* __restrict__ out)
{
    const int b = blockIdx.x;
    float s = 0.f, s2 = 0.f;
    for (int i = 0; i < LN_CHUNKS; ++i) { float2 v = partials[b * LN_CHUNKS + i]; s += v.x; s2 += v.y; }
    const float n = (float)(SDIM * DDIM);
    const float mean = s / n;
    const float inv = rsqrtf(s2 / n - mean * mean + EPS);
    __shared__ float hrow[DDIM];
    const float* row = t + (size_t)b * SDIM * DDIM + (size_t)(SDIM - 1) * DDIM;
    for (int d = threadIdx.x; d < DDIM; d += blockDim.x) hrow[d] = (row[d] - mean) * inv;
    __syncthreads();
    if (threadIdx.x < CDIM) {
        float acc = bd[threadIdx.x];
        for (int d = 0; d < DDIM; ++d)
            acc = fmaf(hrow[d], Wd[(size_t)d * CDIM + threadIdx.x], acc);
        out[(size_t)b * CDIM + threadIdx.x] = acc;
    }
}

extern "C" void kernel_launch(void* const* d_in, const int* in_sizes, int n_in,
                              void* d_out, int out_size, void* d_ws, size_t ws_size,
                              hipStream_t stream)
{
    const int*   x     = (const int*)  d_in[0];
    const float* embed = (const float*)d_in[1];
    const float* pos   = (const float*)d_in[2];
    const float* Wp    = (const float*)d_in[3];
    const float* bp    = (const float*)d_in[4];
    const float* Wm    = (const float*)d_in[5];
    const float* bm    = (const float*)d_in[6];
    const float* W1    = (const float*)d_in[7];
    const float* b1    = (const float*)d_in[8];
    const float* W2    = (const float*)d_in[9];
    const float* b2    = (const float*)d_in[10];
    const float* Wd    = (const float*)d_in[11];
    const float* bd    = (const float*)d_in[12];
    float* out = (float*)d_out;

    const size_t TOK = (size_t)BDIM * SDIM;          // 65536
    const size_t HSZ = TOK * DDIM;                   // 13,107,200 floats
    const size_t PBF = (size_t)BDIM * SDIM * DPAD;   // 14,680,064 shorts

    float*  h     = (float*)d_ws;
    float*  p     = h + HSZ;
    float*  cb    = p + HSZ;
    float*  wmeff = cb + HSZ;
    float2* parts = (float2*)(wmeff + DDIM * DDIM);
    short*  pbf   = (short*)(parts + BDIM * LN_CHUNKS);
    short*  pt    = pbf + PBF;
    const size_t need = (size_t)((char*)(pt + PBF) - (char*)d_ws);
    if (ws_size < need) return;

    wmeff_kernel<<<dim3((DDIM * DDIM + 255) / 256), dim3(256), 0, stream>>>(Wm, wmeff);
    embed_kernel<<<dim3(8192), dim3(256), 0, stream>>>(x, embed, pos, h, (int)HSZ);

    const float inv_scale = 1.0f / sqrtf((float)DDIM);
    const dim3 ggrid(4, 1024);

    for (int st = 0; st < NSTACK; ++st) {
        // p = h @ Wp + bp
        gemm_kernel<<<ggrid, 256, 0, stream>>>(h, Wp, bp, nullptr, p, (int)TOK, DDIM, DDIM, 0);
        // pack/transpose p for MFMA attention
        pack_transpose_kernel<<<dim3(32, 7, 64), 256, 0, stream>>>(p, pbf, pt);
        // cb = softmax(p p^T / scale) @ p   (bf16 MFMA flash)
        attn_kernel<<<dim3(512), 256, 0, stream>>>(pbf, pt, cb, inv_scale);
        // p = cb @ Wm_eff + bm + h   (residual)
        gemm_kernel<<<ggrid, 256, 0, stream>>>(cb, wmeff, bm, h, p, (int)TOK, DDIM, DDIM, 0);
        ln_partial<<<dim3(LN_CHUNKS, BDIM), 256, 0, stream>>>(p, parts);
        ln_norm<<<dim3(32, BDIM), 256, 0, stream>>>(p, parts, h);
        // cb = relu(h @ W1 + b1)
        gemm_kernel<<<ggrid, 256, 0, stream>>>(h, W1, b1, nullptr, cb, (int)TOK, DDIM, DDIM, 1);
        // p = cb @ W2 + b2 + h
        gemm_kernel<<<ggrid, 256, 0, stream>>>(cb, W2, b2, h, p, (int)TOK, DDIM, DDIM, 0);
        ln_partial<<<dim3(LN_CHUNKS, BDIM), 256, 0, stream>>>(p, parts);
        if (st < NSTACK - 1) {
            ln_norm<<<dim3(32, BDIM), 256, 0, stream>>>(p, parts, h);
        } else {
            final_kernel<<<dim3(BDIM), 64, 0, stream>>>(p, parts, Wd, bd, out);
        }
    }
}

// Round 3
// 847.319 us; speedup vs baseline: 25.2044x; 2.2305x over previous
//
#include <hip/hip_runtime.h>
#include <cstddef>
#include <cstdint>
#include <cmath>

// Problem constants
#define BDIM  64
#define SDIM  1024
#define DDIM  200
#define DPAD  224            // 7 x 32 k-steps, 14 x 16 n-tiles
#define CDIM  31
#define NSTACK 2
#define EPS   1e-5f
#define LN_N  204800.0f      // 1024*200 elements per batch LN plane

typedef __attribute__((ext_vector_type(8))) short short8;
typedef __attribute__((ext_vector_type(4))) short short4_t;
typedef __attribute__((ext_vector_type(4))) float f32x4;

__device__ __forceinline__ short f2bf(float f) {
    union { float f; unsigned u; } v; v.f = f;
    unsigned r = v.u + 0x7FFFu + ((v.u >> 16) & 1u);   // RNE
    return (short)(r >> 16);
}
__device__ __forceinline__ float bf2f(short s) {
    union { unsigned u; float f; } v; v.u = ((unsigned)(unsigned short)s) << 16;
    return v.f;
}

// ---------------- prep: padded bf16 transposed weights + padded fp32 biases ------
// Wt_x[n*224+k] = W_x[k*200+n] (n<200,k<200) else 0 ; WtM folds the 8 Wm blocks.
__global__ void prep_kernel(const float* __restrict__ Wp, const float* __restrict__ bp,
                            const float* __restrict__ Wm, const float* __restrict__ bm,
                            const float* __restrict__ W1, const float* __restrict__ b1,
                            const float* __restrict__ W2, const float* __restrict__ b2,
                            short* __restrict__ WtP, short* __restrict__ WtM,
                            short* __restrict__ Wt1, short* __restrict__ Wt2,
                            float* __restrict__ bpP, float* __restrict__ bmP,
                            float* __restrict__ b1P, float* __restrict__ b2P)
{
    int idx = blockIdx.x * 256 + threadIdx.x;
    if (idx >= DPAD * DPAD) return;
    int n = idx / DPAD, k = idx - n * DPAD;
    bool valid = (n < DDIM) && (k < DDIM);
    WtP[idx] = valid ? f2bf(Wp[(size_t)k * DDIM + n]) : 0;
    Wt1[idx] = valid ? f2bf(W1[(size_t)k * DDIM + n]) : 0;
    Wt2[idx] = valid ? f2bf(W2[(size_t)k * DDIM + n]) : 0;
    float s = 0.f;
    if (valid) {
        #pragma unroll
        for (int blk = 0; blk < 8; ++blk)
            s += Wm[(size_t)(blk * DDIM + k) * DDIM + n];
    }
    WtM[idx] = valid ? f2bf(s) : 0;
    if (idx < DPAD) {
        bpP[idx] = idx < DDIM ? bp[idx] : 0.f;
        bmP[idx] = idx < DDIM ? bm[idx] : 0.f;
        b1P[idx] = idx < DDIM ? b1[idx] : 0.f;
        b2P[idx] = idx < DDIM ? b2[idx] : 0.f;
    }
}

// ---------------- h_bf = bf16(embed[x] + pos), zero-padded to 224 ----------------
__global__ void embed_kernel(const int* __restrict__ x, const float* __restrict__ embed,
                             const float* __restrict__ pos, short* __restrict__ h)
{
    const int row = blockIdx.x;            // b*S + s
    const int n = threadIdx.x;
    if (n >= DPAD) return;
    const int s = row & (SDIM - 1);
    const int tok = x[row];
    float v = (n < DDIM) ? embed[(size_t)tok * DDIM + n] + pos[(size_t)s * DDIM + n] : 0.f;
    h[(size_t)row * DPAD + n] = (n < DDIM) ? f2bf(v) : (short)0;
}

// ---------------- bf16 MFMA GEMM: out[M,224] = act[M,224] @ W^T(Wt) + bias -------
// A-operand = Wt rows (n), B-operand = activation rows (m); D[row=n][col=m].
// Optional: residual add (res), relu, transposed write (pt), LN stats (parts).
__global__ __launch_bounds__(256, 2)
void gemm_bf(const short* __restrict__ act, const short* __restrict__ Wt,
             const float* __restrict__ bias, const short* __restrict__ res,
             short* __restrict__ out, short* __restrict__ pt,
             float* __restrict__ parts, int doRelu)
{
    const int tid  = threadIdx.x;
    const int wave = tid >> 6, lane = tid & 63;
    const int lo   = lane & 15, hi = lane >> 4;
    const int m0   = blockIdx.x * 128 + wave * 32;

    f32x4 acc[2][14];
    #pragma unroll
    for (int mt = 0; mt < 2; ++mt)
        #pragma unroll
        for (int nt = 0; nt < 14; ++nt) acc[mt][nt] = (f32x4){0.f, 0.f, 0.f, 0.f};

    #pragma unroll
    for (int ks = 0; ks < 7; ++ks) {
        short8 bfrag[2];
        #pragma unroll
        for (int mt = 0; mt < 2; ++mt)
            bfrag[mt] = *(const short8*)(act + (size_t)(m0 + mt * 16 + lo) * DPAD + ks * 32 + hi * 8);
        #pragma unroll
        for (int nt = 0; nt < 14; ++nt) {
            short8 afrag = *(const short8*)(Wt + (size_t)(nt * 16 + lo) * DPAD + ks * 32 + hi * 8);
            acc[0][nt] = __builtin_amdgcn_mfma_f32_16x16x32_bf16(afrag, bfrag[0], acc[0][nt], 0, 0, 0);
            acc[1][nt] = __builtin_amdgcn_mfma_f32_16x16x32_bf16(afrag, bfrag[1], acc[1][nt], 0, 0, 0);
        }
    }

    float s = 0.f, s2 = 0.f;
    #pragma unroll
    for (int mt = 0; mt < 2; ++mt) {
        const int m = m0 + mt * 16 + lo;
        #pragma unroll
        for (int nt = 0; nt < 14; ++nt) {
            const int nb = nt * 16 + hi * 4;
            float v[4];
            #pragma unroll
            for (int r = 0; r < 4; ++r) v[r] = acc[mt][nt][r] + bias[nb + r];
            if (res) {
                short4_t rv = *(const short4_t*)(res + (size_t)m * DPAD + nb);
                #pragma unroll
                for (int r = 0; r < 4; ++r) v[r] += bf2f(rv[r]);
            }
            if (doRelu)
                #pragma unroll
                for (int r = 0; r < 4; ++r) v[r] = fmaxf(v[r], 0.f);
            if (parts)
                #pragma unroll
                for (int r = 0; r < 4; ++r) { s += v[r]; s2 = fmaf(v[r], v[r], s2); }
            short4_t o4;
            #pragma unroll
            for (int r = 0; r < 4; ++r) o4[r] = f2bf(v[r]);
            *(short4_t*)(out + (size_t)m * DPAD + nb) = o4;
            if (pt) {
                const int bb = m >> 10, sloc = m & (SDIM - 1);
                #pragma unroll
                for (int r = 0; r < 4; ++r)
                    pt[((size_t)bb * DPAD + nb + r) * SDIM + sloc] = o4[r];
            }
        }
    }

    if (parts) {
        __shared__ float rs[4], rq[4];
        #pragma unroll
        for (int off = 32; off; off >>= 1) {
            s  += __shfl_down(s, off);
            s2 += __shfl_down(s2, off);
        }
        if (lane == 0) { rs[wave] = s; rq[wave] = s2; }
        __syncthreads();
        if (tid == 0) {
            const int bb = (blockIdx.x * 128) >> 10;
            atomicAdd(&parts[bb * 2],     rs[0] + rs[1] + rs[2] + rs[3]);
            atomicAdd(&parts[bb * 2 + 1], rq[0] + rq[1] + rq[2] + rq[3]);
        }
    }
}

// ---------------- fused MFMA flash attention (bf16 in/out) ----------------
#define KSTRIDE 232
__global__ __launch_bounds__(256, 2)
void attn_kernel(const short* __restrict__ pbf, const short* __restrict__ pt,
                 short* __restrict__ c, float inv_scale)
{
    __shared__ short K_lds[64 * KSTRIDE];
    __shared__ short Vt_lds[208 * 64];

    const int bid = blockIdx.x;
    const int wg  = (bid & 7) * 64 + (bid >> 3);
    const int b   = wg >> 3;
    const int q0  = (wg & 7) * 128;

    const int tid  = threadIdx.x;
    const int wave = tid >> 6;
    const int lane = tid & 63;
    const int lo   = lane & 15;
    const int hi   = lane >> 4;

    const short* pb  = pbf + (size_t)b * SDIM * DPAD;
    const short* ptb = pt  + (size_t)b * DPAD * SDIM;

    short8 qf[2][7];
    #pragma unroll
    for (int rt = 0; rt < 2; ++rt)
        #pragma unroll
        for (int ks = 0; ks < 7; ++ks)
            qf[rt][ks] = *(const short8*)(pb + (size_t)(q0 + wave * 32 + rt * 16 + lo) * DPAD
                                          + ks * 32 + hi * 8);

    f32x4 o[2][13];
    float m[2][4], ell[2][4];
    #pragma unroll
    for (int rt = 0; rt < 2; ++rt) {
        #pragma unroll
        for (int n = 0; n < 13; ++n) o[rt][n] = (f32x4){0.f, 0.f, 0.f, 0.f};
        #pragma unroll
        for (int r = 0; r < 4; ++r) { m[rt][r] = -1e30f; ell[rt][r] = 0.f; }
    }

    for (int kt = 0; kt < 16; ++kt) {
        const int k0 = kt * 64;
        __syncthreads();

        for (int i = tid; i < 1792; i += 256) {
            int r  = i / 28;
            int c8 = i - r * 28;
            short8 v = *(const short8*)(pb + (size_t)(k0 + r) * DPAD + c8 * 8);
            *(short8*)(&K_lds[r * KSTRIDE + c8 * 8]) = v;
        }
        for (int i = tid; i < 1664; i += 256) {
            int d  = i >> 3;
            int c8 = i & 7;
            short8 v = *(const short8*)(ptb + (size_t)d * SDIM + k0 + c8 * 8);
            int e = (d * 64 + c8 * 8) ^ ((d & 7) << 3);
            *(short8*)(&Vt_lds[e]) = v;
        }
        __syncthreads();

        f32x4 sacc[2][4];
        #pragma unroll
        for (int rt = 0; rt < 2; ++rt)
            #pragma unroll
            for (int t = 0; t < 4; ++t) sacc[rt][t] = (f32x4){0.f, 0.f, 0.f, 0.f};
        #pragma unroll
        for (int t = 0; t < 4; ++t)
            #pragma unroll
            for (int ks = 0; ks < 7; ++ks) {
                short8 kf = *(const short8*)(&K_lds[(t * 16 + lo) * KSTRIDE + ks * 32 + hi * 8]);
                sacc[0][t] = __builtin_amdgcn_mfma_f32_16x16x32_bf16(qf[0][ks], kf, sacc[0][t], 0, 0, 0);
                sacc[1][t] = __builtin_amdgcn_mfma_f32_16x16x32_bf16(qf[1][ks], kf, sacc[1][t], 0, 0, 0);
            }
        __syncthreads();

        #pragma unroll
        for (int rt = 0; rt < 2; ++rt) {
            float mx[4], al[4], rsum[4];
            #pragma unroll
            for (int t = 0; t < 4; ++t)
                #pragma unroll
                for (int r = 0; r < 4; ++r) sacc[rt][t][r] *= inv_scale;
            #pragma unroll
            for (int r = 0; r < 4; ++r)
                mx[r] = fmaxf(fmaxf(sacc[rt][0][r], sacc[rt][1][r]),
                              fmaxf(sacc[rt][2][r], sacc[rt][3][r]));
            #pragma unroll
            for (int off = 1; off <= 8; off <<= 1)
                #pragma unroll
                for (int r = 0; r < 4; ++r)
                    mx[r] = fmaxf(mx[r], __shfl_xor(mx[r], off));
            #pragma unroll
            for (int r = 0; r < 4; ++r) {
                float mn = fmaxf(m[rt][r], mx[r]);
                al[r] = __expf(m[rt][r] - mn);
                m[rt][r] = mn;
                ell[rt][r] *= al[r];
            }
            #pragma unroll
            for (int t = 0; t < 4; ++t)
                #pragma unroll
                for (int r = 0; r < 4; ++r)
                    sacc[rt][t][r] = __expf(sacc[rt][t][r] - m[rt][r]);
            #pragma unroll
            for (int r = 0; r < 4; ++r)
                rsum[r] = sacc[rt][0][r] + sacc[rt][1][r] + sacc[rt][2][r] + sacc[rt][3][r];
            #pragma unroll
            for (int off = 1; off <= 8; off <<= 1)
                #pragma unroll
                for (int r = 0; r < 4; ++r)
                    rsum[r] += __shfl_xor(rsum[r], off);
            #pragma unroll
            for (int r = 0; r < 4; ++r) ell[rt][r] += rsum[r];
            #pragma unroll
            for (int n = 0; n < 13; ++n)
                #pragma unroll
                for (int r = 0; r < 4; ++r) o[rt][n][r] *= al[r];
            const int pbase = wave * 2048 + rt * 1024;
            #pragma unroll
            for (int t = 0; t < 4; ++t)
                #pragma unroll
                for (int r = 0; r < 4; ++r) {
                    int qrow = hi * 4 + r;
                    int e = pbase + ((qrow * 64 + t * 16 + lo) ^ ((qrow & 7) << 3));
                    K_lds[e] = f2bf(sacc[rt][t][r]);
                }
        }

        #pragma unroll
        for (int ks2 = 0; ks2 < 2; ++ks2) {
            const int poff = (lo * 64 + ks2 * 32 + hi * 8) ^ ((lo & 7) << 3);
            short8 pa0 = *(const short8*)(&K_lds[wave * 2048 + poff]);
            short8 pa1 = *(const short8*)(&K_lds[wave * 2048 + 1024 + poff]);
            #pragma unroll
            for (int n = 0; n < 13; ++n) {
                short8 vf = *(const short8*)(&Vt_lds[((n * 16 + lo) * 64 + ks2 * 32 + hi * 8)
                                                     ^ ((lo & 7) << 3)]);
                o[0][n] = __builtin_amdgcn_mfma_f32_16x16x32_bf16(pa0, vf, o[0][n], 0, 0, 0);
                o[1][n] = __builtin_amdgcn_mfma_f32_16x16x32_bf16(pa1, vf, o[1][n], 0, 0, 0);
            }
        }
    }

    #pragma unroll
    for (int rt = 0; rt < 2; ++rt) {
        float inv_l[4];
        #pragma unroll
        for (int r = 0; r < 4; ++r) inv_l[r] = 1.f / ell[rt][r];
        #pragma unroll
        for (int n = 0; n < 13; ++n) {
            int dcol = n * 16 + lo;
            #pragma unroll
            for (int r = 0; r < 4; ++r) {
                size_t row = (size_t)b * SDIM + q0 + wave * 32 + rt * 16 + hi * 4 + r;
                c[row * DPAD + dcol] = f2bf(o[rt][n][r] * inv_l[r]);
            }
        }
        // zero pad cols 208..223
        #pragma unroll
        for (int r = 0; r < 4; ++r) {
            size_t row = (size_t)b * SDIM + q0 + wave * 32 + rt * 16 + hi * 4 + r;
            c[row * DPAD + 208 + lo] = 0;
        }
    }
}

// ---------------- LN normalize (bf16 in/out), pad cols -> 0 ----------------
__global__ void ln_norm_bf(const short* __restrict__ y, const float* __restrict__ parts,
                           short* __restrict__ h)
{
    const int total = BDIM * SDIM * (DPAD / 4);   // short4 groups
    for (int i = blockIdx.x * blockDim.x + threadIdx.x; i < total;
         i += gridDim.x * blockDim.x) {
        const int row = i / (DPAD / 4);
        const int g   = i - row * (DPAD / 4);
        const int n0  = g * 4;
        const int b   = row >> 10;
        short4_t o4;
        if (n0 >= DDIM) {
            o4[0] = o4[1] = o4[2] = o4[3] = 0;
        } else {
            const float sum = parts[b * 2], sq = parts[b * 2 + 1];
            const float mean = sum / LN_N;
            const float inv  = rsqrtf(sq / LN_N - mean * mean + EPS);
            short4_t v4 = *(const short4_t*)(y + (size_t)i * 4);
            #pragma unroll
            for (int r = 0; r < 4; ++r) o4[r] = f2bf((bf2f(v4[r]) - mean) * inv);
        }
        *(short4_t*)(h + (size_t)i * 4) = o4;
    }
}

// ---------------- final: normalize row S-1 only + head ----------------
__global__ void final_kernel(const short* __restrict__ y, const float* __restrict__ parts,
                             const float* __restrict__ Wd, const float* __restrict__ bd,
                             float* __restrict__ out)
{
    const int b = blockIdx.x;
    const float sum = parts[b * 2], sq = parts[b * 2 + 1];
    const float mean = sum / LN_N;
    const float inv  = rsqrtf(sq / LN_N - mean * mean + EPS);
    __shared__ float hrow[DDIM];
    const short* row = y + ((size_t)b * SDIM + SDIM - 1) * DPAD;
    for (int d = threadIdx.x; d < DDIM; d += blockDim.x)
        hrow[d] = (bf2f(row[d]) - mean) * inv;
    __syncthreads();
    if (threadIdx.x < CDIM) {
        float acc = bd[threadIdx.x];
        for (int d = 0; d < DDIM; ++d)
            acc = fmaf(hrow[d], Wd[(size_t)d * CDIM + threadIdx.x], acc);
        out[(size_t)b * CDIM + threadIdx.x] = acc;
    }
}

extern "C" void kernel_launch(void* const* d_in, const int* in_sizes, int n_in,
                              void* d_out, int out_size, void* d_ws, size_t ws_size,
                              hipStream_t stream)
{
    const int*   x     = (const int*)  d_in[0];
    const float* embed = (const float*)d_in[1];
    const float* pos   = (const float*)d_in[2];
    const float* Wp    = (const float*)d_in[3];
    const float* bp    = (const float*)d_in[4];
    const float* Wm    = (const float*)d_in[5];
    const float* bm    = (const float*)d_in[6];
    const float* W1    = (const float*)d_in[7];
    const float* b1    = (const float*)d_in[8];
    const float* W2    = (const float*)d_in[9];
    const float* b2    = (const float*)d_in[10];
    const float* Wd    = (const float*)d_in[11];
    const float* bd    = (const float*)d_in[12];
    float* out = (float*)d_out;

    const size_t HB = (size_t)BDIM * SDIM * DPAD;     // 14,680,064 bf16 elems

    short* h_bf  = (short*)d_ws;
    short* p_bf  = h_bf  + HB;
    short* pt    = p_bf  + HB;
    short* cb_bf = pt    + HB;
    short* y_bf  = cb_bf + HB;
    short* WtP   = y_bf  + HB;
    short* WtM   = WtP + DPAD * DPAD;
    short* Wt1   = WtM + DPAD * DPAD;
    short* Wt2   = Wt1 + DPAD * DPAD;
    float* bpP   = (float*)(Wt2 + DPAD * DPAD);
    float* bmP   = bpP + DPAD;
    float* b1P   = bmP + DPAD;
    float* b2P   = b1P + DPAD;
    float* parts = b2P + DPAD;                        // 4 stacks-halves x 64 x 2 floats
    const size_t need = (size_t)((char*)(parts + 4 * BDIM * 2) - (char*)d_ws);
    if (ws_size < need) return;

    prep_kernel<<<dim3((DPAD * DPAD + 255) / 256), dim3(256), 0, stream>>>(
        Wp, bp, Wm, bm, W1, b1, W2, b2, WtP, WtM, Wt1, Wt2, bpP, bmP, b1P, b2P);
    embed_kernel<<<dim3(BDIM * SDIM), dim3(256), 0, stream>>>(x, embed, pos, h_bf);
    hipMemsetAsync(parts, 0, 4 * BDIM * 2 * sizeof(float), stream);

    const float inv_scale = 1.0f / sqrtf((float)DDIM);

    for (int st = 0; st < NSTACK; ++st) {
        float* partsA = parts + (st * 2 + 0) * BDIM * 2;
        float* partsB = parts + (st * 2 + 1) * BDIM * 2;
        // p = h @ Wp + bp  (+ transposed write for attention V^T)
        gemm_bf<<<dim3(512), dim3(256), 0, stream>>>(h_bf, WtP, bpP, nullptr, p_bf, pt, nullptr, 0);
        // cb = softmax(p p^T / scale) @ p
        attn_kernel<<<dim3(512), dim3(256), 0, stream>>>(p_bf, pt, cb_bf, inv_scale);
        // y = cb @ Wm_eff + bm + h   (+ LN stats)
        gemm_bf<<<dim3(512), dim3(256), 0, stream>>>(cb_bf, WtM, bmP, h_bf, y_bf, nullptr, partsA, 0);
        ln_norm_bf<<<dim3(2048), dim3(256), 0, stream>>>(y_bf, partsA, h_bf);
        // cb = relu(h @ W1 + b1)
        gemm_bf<<<dim3(512), dim3(256), 0, stream>>>(h_bf, Wt1, b1P, nullptr, cb_bf, nullptr, nullptr, 1);
        // y = cb @ W2 + b2 + h  (+ LN stats)
        gemm_bf<<<dim3(512), dim3(256), 0, stream>>>(cb_bf, Wt2, b2P, h_bf, y_bf, nullptr, partsB, 0);
        if (st < NSTACK - 1) {
            ln_norm_bf<<<dim3(2048), dim3(256), 0, stream>>>(y_bf, partsB, h_bf);
        } else {
            final_kernel<<<dim3(BDIM), dim3(64), 0, stream>>>(y_bf, partsB, Wd, bd, out);
        }
    }
}